// Round 15
// baseline (146.926 us; speedup 1.0000x reference)
//
#include <hip/hip_runtime.h>
#include <hip/hip_bf16.h>
#include <math.h>

// Problem constants
#define L_SEQ   1024
#define NB      8
#define H_DIM   300
#define KWIN    5
#define NREL    11          // 2K+1
#define PDIM    50
#define NC      11234       // band pair count for L=1024, K=5
#define BNC     (NB*NC)     // 89872
#define LN_EPS  1e-5f

#define KPAD    320         // K padded with zeros in [300,320)
#define WKSTR   320         // Wb k-stride (shorts)
#define WNPAD   320         // Wb padded n rows

#define ITILE   16          // i rows per block
#define HROWS   26          // hc halo rows: i0-5 .. i0+20
#define ZROW    42          // zero rows 42..47 (MFMA clamp)
#define XROWS   64          // 0..15 Ae/he, 16..41 Ac/hc, 42..47 zero,
                            // 48..58 Pb (bf16 prel), 59 ones, 60..63 zero
#define XSTR    328         // X row stride in shorts
#define NPAIR   (ITILE*NREL)  // 176
#define NCHUNK  (HROWS*76)    // 1976 staging chunks

// Stats table layout (floats): SS[0..63], S[64..127],
// Dec[128 + row*28 + (col-16)] row<16 col 16..41,
// Dep[576 + row*12 + (col-48)] row<16 col 48..58,
// Dcp[768 + (row-16)*12 + (col-48)] row 16..41 col 48..58.  total 1080 -> 1088
#define STSZ 1088

// Workspace layout (float offsets)
#define WB_OFF   2048       // prelbf (11*328 shorts) lives at 0

typedef __attribute__((ext_vector_type(8))) short s16x8;
typedef __attribute__((ext_vector_type(4))) short s16x4;
typedef __attribute__((ext_vector_type(4))) float f32x4;

__device__ __forceinline__ short f2bf(float f) {
    unsigned u = __float_as_uint(f);
    u += 0x7fffu + ((u >> 16) & 1u);
    return (short)(u >> 16);
}
__device__ __forceinline__ float bf2f(short s) {
    return __uint_as_float(((unsigned)(unsigned short)s) << 16);
}

// band row start: first linear index n of row i
__device__ __forceinline__ int rowstart(int i) {
    if (i < 5)     return 6 * i + (i * (i - 1)) / 2;
    if (i <= 1018) return 40 + (i - 5) * 11;
    int d = i - 1019;
    return 11194 + d * 10 - (d * (d - 1)) / 2;
}

// predicated scatter of one Gram cell into the compact stats table
__device__ __forceinline__ void stat_write(float* ST, int row, int col, float v) {
    if (col == 59 && row < 59) ST[64 + row] = v;                       // S
    if (col == row && row < 59) ST[row] = v;                           // SS
    if (row < 16) {
        if (col >= 16 && col < 42)      ST[128 + row * 28 + (col - 16)] = v;  // Dec
        else if (col >= 48 && col < 59) ST[576 + row * 12 + (col - 48)] = v;  // Dep
    } else if (row < 42 && col >= 48 && col < 59) {
        ST[768 + (row - 16) * 12 + (col - 48)] = v;                    // Dcp
    }
}

// ---------------------------------------------------------------------------
// Kernel 1: prep (unchanged from r12).
__global__ __launch_bounds__(256) void prep_kernel(
    const float* __restrict__ pos_W, const float* __restrict__ W1,
    const float* __restrict__ b1, short* __restrict__ prelbf,
    short* __restrict__ Wb)
{
    if (blockIdx.x < 15) {
        __shared__ float semb[NREL * PDIM];
        for (int t = threadIdx.x; t < NREL * PDIM; t += 256) {
            int r = t / PDIM, d = t % PDIM;
            float acc = 0.f;
#pragma unroll
            for (int r2 = 0; r2 < NREL; ++r2) {
                float cnt = (float)(L_SEQ - abs(r2 - KWIN));
                int dr = r - r2;
                acc += cnt * expf(-(float)(dr * dr)) * pos_W[r2 * PDIM + d];
            }
            semb[t] = acc;
        }
        __syncthreads();
        int t = blockIdx.x * 256 + threadIdx.x;
        if (t < NREL * XSTR) {
            int r = t / XSTR, h = t % XSTR;
            float acc = 0.f;
            if (h < H_DIM) {
                acc = b1[h];
                const float* wrow = W1 + (size_t)h * 650 + 600;
                const float* em = semb + r * PDIM;
#pragma unroll 10
                for (int d = 0; d < PDIM; ++d) acc += wrow[d] * em[d];
            }
            prelbf[t] = (h < H_DIM) ? f2bf(acc) : (short)0;
        }
    } else {
        int id = (blockIdx.x - 15) * 256 + threadIdx.x;
        if (id < 2 * WNPAD * WKSTR) {
            int z = id / (WNPAD * WKSTR);
            int rem = id % (WNPAD * WKSTR);
            int n = rem / WKSTR, k = rem % WKSTR;
            float v = (n < H_DIM && k < H_DIM) ? W1[(size_t)n * 650 + z * H_DIM + k] : 0.f;
            Wb[id] = f2bf(v);
        }
    }
}

// ---------------------------------------------------------------------------
// Kernel 2: fused GEMM + Gram(compact stats) + dual-pair epilogue.
// Block = (b, i-tile of 16), 512 threads, grid 512.
// LDS ~50 KB -> 3 blocks/CU (24 waves/CU), up from r12's 2 (16 waves).
__global__ __launch_bounds__(512) void fused_kernel(
    const float* __restrict__ h_e, const float* __restrict__ h_c,
    const float* __restrict__ h_share, const short* __restrict__ Wb,
    const short* __restrict__ prelbf,
    const float* __restrict__ ln_g, const float* __restrict__ ln_b,
    const float* __restrict__ W2, const float* __restrict__ b2,
    float* __restrict__ out, float* __restrict__ posout)
{
    __shared__ __align__(16) short X[XROWS * XSTR];   // 41984 B
    __shared__ __align__(16) float ST[STSZ];          // 4352 B
    __shared__ __align__(16) float SG[320];
    __shared__ __align__(16) float SB[320];
    __shared__ __align__(16) float SW[320];

    const int tid = threadIdx.x;
    const int b   = blockIdx.x >> 6;
    const int i0  = (blockIdx.x & 63) * ITILE;

    // ---- staging: issue all global loads first (predicated), then convert.
    const float4 z4 = make_float4(0.f, 0.f, 0.f, 0.f);
    float4 Lhs[4], Lhc[4], Lhe[4];
    int  sA[4], kcA[4];
    bool heA[4];
#pragma unroll
    for (int u = 0; u < 4; ++u) {
        const int t = tid + u * 512;
        const int s = t / 76, kc = (t % 76) * 4;
        sA[u] = s; kcA[u] = kc;
        const int g = i0 - KWIN + s;
        const bool inb = (t < NCHUNK) && (kc < H_DIM) && (g >= 0) && (g < L_SEQ);
        const bool ise = inb && (s >= 5) && (s < 5 + ITILE);
        heA[u] = (s >= 5) && (s < 5 + ITILE);
        const size_t off = inb ? (((size_t)b * L_SEQ + g) * H_DIM + kc) : 0;
        Lhs[u] = inb ? *(const float4*)(h_share + off) : z4;
        Lhc[u] = inb ? *(const float4*)(h_c + off)     : z4;
        Lhe[u] = ise ? *(const float4*)(h_e + off)     : z4;
    }

    // ---- zero-fill: rows 42..47 & 60..63 (10*41 chunks) + rows 0..41 cols [304,328)
    for (int t = tid; t < 536; t += 512) {
        int row, c;
        if (t < 410) { int rr2 = t / 41; row = rr2 < 6 ? 42 + rr2 : 60 + (rr2 - 6); c = (t % 41) * 8; }
        else         { int u = t - 410; row = u / 3; c = 304 + (u % 3) * 8; }
        *(s16x8*)&X[row * XSTR + c] = (s16x8){0,0,0,0,0,0,0,0};
    }
    // ---- ones row (59)
    for (int t = tid; t < XSTR; t += 512)
        X[59 * XSTR + t] = (t < H_DIM) ? (short)0x3F80 : (short)0;
    // ---- Pb rows 48..58
    for (int t = tid; t < NREL * 41; t += 512) {
        int r = t / 41, c = (t % 41) * 8;
        *(s16x8*)&X[(48 + r) * XSTR + c] = *(const s16x8*)(prelbf + r * XSTR + c);
    }
    // ---- LN params
    if (tid < 320) {
        bool v = tid < H_DIM;
        SG[tid] = v ? ln_g[tid] : 0.f;
        SB[tid] = v ? ln_b[tid] : 0.f;
        SW[tid] = v ? W2[tid]   : 0.f;
    }
    // ---- convert + store staged rows
#pragma unroll
    for (int u = 0; u < 4; ++u) {
        const int t = tid + u * 512;
        if (t < NCHUNK) {
            const int s = sA[u], kc = kcA[u];
            s16x4 vc = { f2bf(Lhc[u].x + Lhs[u].x), f2bf(Lhc[u].y + Lhs[u].y),
                         f2bf(Lhc[u].z + Lhs[u].z), f2bf(Lhc[u].w + Lhs[u].w) };
            *(s16x4*)&X[(16 + s) * XSTR + kc] = vc;
            if (heA[u]) {
                s16x4 ve = { f2bf(Lhe[u].x + Lhs[u].x), f2bf(Lhe[u].y + Lhs[u].y),
                             f2bf(Lhe[u].z + Lhs[u].z), f2bf(Lhe[u].w + Lhs[u].w) };
                *(s16x4*)&X[(s - 5) * XSTR + kc] = ve;
            }
        }
    }
    __syncthreads();

    // ---- Main GEMM (r12 structure). 8 waves: wz = wave>>2, nsl = (wave&3)*80.
    const int wave = tid >> 6, lane = tid & 63;
    const int fr = lane & 15, fq = lane >> 4;
    const int wz  = wave >> 2;
    const int nsl = (wave & 3) * 80;
    const short* wbase = Wb + ((size_t)(wz * WNPAD + nsl + fr)) * WKSTR + fq * 8;

    const int mrow0 = wz ? (16 + fr) : fr;
    const int mrow1 = (fr < 10) ? (32 + fr) : ZROW;   // wz==1 only

    f32x4 acc0[5] = {};
    f32x4 acc1[5] = {};

    for (int k0 = 0; k0 < KPAD; k0 += 32) {
        s16x8 bf[5];
#pragma unroll
        for (int nt = 0; nt < 5; ++nt)
            bf[nt] = *(const s16x8*)(wbase + (size_t)nt * 16 * WKSTR + k0);
        s16x8 af0 = *(const s16x8*)&X[mrow0 * XSTR + k0 + fq * 8];
#pragma unroll
        for (int nt = 0; nt < 5; ++nt)
            acc0[nt] = __builtin_amdgcn_mfma_f32_16x16x32_bf16(af0, bf[nt], acc0[nt], 0, 0, 0);
        if (wz) {
            s16x8 af1 = *(const s16x8*)&X[mrow1 * XSTR + k0 + fq * 8];
#pragma unroll
            for (int nt = 0; nt < 5; ++nt)
                acc1[nt] = __builtin_amdgcn_mfma_f32_16x16x32_bf16(af1, bf[nt], acc1[nt], 0, 0, 0);
        }
    }
    __syncthreads();   // all waves done reading X inputs

    // ---- write Ae/Ac into X (bf16). C/D: col = nsl+nt*16+fr, row = fq*4+r2
#pragma unroll
    for (int nt = 0; nt < 5; ++nt) {
        const int col = nsl + nt * 16 + fr;     // cols>=300 compute to 0
        if (!wz) {
#pragma unroll
            for (int r2 = 0; r2 < 4; ++r2)
                X[(fq * 4 + r2) * XSTR + col] = f2bf(acc0[nt][r2]);
        } else {
#pragma unroll
            for (int r2 = 0; r2 < 4; ++r2)
                X[(16 + fq * 4 + r2) * XSTR + col] = f2bf(acc0[nt][r2]);
#pragma unroll
            for (int r2 = 0; r2 < 4; ++r2) {
                int rw = 32 + fq * 4 + r2;
                if (rw < 42) X[rw * XSTR + col] = f2bf(acc1[nt][r2]);
            }
        }
    }
    __syncthreads();

    // ---- Gram mini-GEMM: G = X . X^T over 64 rows, scatter needed stats only.
    {
        const int mf  = wave & 3;
        const int nf0 = (wave >> 2) * 2;
        f32x4 ga = {}, gb = {};
        for (int k0 = 0; k0 < KPAD; k0 += 32) {
            s16x8 av = *(const s16x8*)&X[(mf * 16 + fr) * XSTR + k0 + fq * 8];
            s16x8 b0 = *(const s16x8*)&X[(nf0 * 16 + fr) * XSTR + k0 + fq * 8];
            s16x8 b1 = *(const s16x8*)&X[((nf0 + 1) * 16 + fr) * XSTR + k0 + fq * 8];
            ga = __builtin_amdgcn_mfma_f32_16x16x32_bf16(av, b0, ga, 0, 0, 0);
            gb = __builtin_amdgcn_mfma_f32_16x16x32_bf16(av, b1, gb, 0, 0, 0);
        }
        const int col0 = nf0 * 16 + fr, col1 = col0 + 16;
#pragma unroll
        for (int r2 = 0; r2 < 4; ++r2) {
            const int row = mf * 16 + fq * 4 + r2;
            stat_write(ST, row, col0, ga[r2]);
            stat_write(ST, row, col1, gb[r2]);
        }
    }
    __syncthreads();

    // ---- Epilogue: 2 pairs per 16-lane quad, 32 quads, 3 rounds (176 pairs).
    const int quad = lane >> 4, fl = lane & 15;
    const int qq = wave * 4 + quad;            // 0..31
    const float b2v = b2[0];
    const float inv = 1.f / (float)H_DIM;

    for (int round = 0; round < 3; ++round) {
        const int qb = round * 64 + qq * 2;
        int di[2], rr[2], jj[2], ii[2];
        bool act[2];
        float rsig[2], nmrs[2];
        int ea[2], ca[2], pa[2];
#pragma unroll
        for (int u = 0; u < 2; ++u) {
            int q = qb + u;
            int qc = q < NPAIR - 1 ? q : NPAIR - 1;
            di[u] = qc / NREL; rr[u] = qc % NREL;
            ii[u] = i0 + di[u];
            jj[u] = ii[u] - KWIN + rr[u];
            act[u] = (q < NPAIR) && (jj[u] >= 0) && (jj[u] < L_SEQ);

            const int iA = di[u], jA = 16 + di[u] + rr[u], pA = 48 + rr[u];
            const float Se  = ST[64 + iA];
            const float Sc  = ST[64 + jA];
            const float Sp  = ST[64 + pA];
            const float SSe = ST[iA];
            const float SSc = ST[jA];
            const float SSp = ST[pA];
            const float Dec = ST[128 + iA * 28 + (jA - 16)];
            const float Dep = ST[576 + iA * 12 + rr[u]];
            const float Dcp = ST[768 + (jA - 16) * 12 + rr[u]];
            const float mu  = (Se + Sc + Sp) * inv;
            const float ssv = SSe + SSc + SSp + 2.f * (Dec + Dep + Dcp);
            rsig[u] = rsqrtf(ssv * inv - mu * mu + LN_EPS);
            nmrs[u] = -mu * rsig[u];
            ea[u] = iA * XSTR; ca[u] = jA * XSTR; pa[u] = pA * XSTR;
        }

        float acc0e = 0.f, acc1e = 0.f;
#pragma unroll
        for (int w5 = 0; w5 < 5; ++w5) {
            const int c = w5 * 64 + fl * 4;     // 0..316, zero-padded
            s16x4 a0 = *(const s16x4*)&X[ea[0] + c];
            s16x4 d0 = *(const s16x4*)&X[ca[0] + c];
            s16x4 p0 = *(const s16x4*)&X[pa[0] + c];
            s16x4 a1 = *(const s16x4*)&X[ea[1] + c];
            s16x4 d1 = *(const s16x4*)&X[ca[1] + c];
            s16x4 p1 = *(const s16x4*)&X[pa[1] + c];
            float4 g  = *(const float4*)&SG[c];
            float4 bb = *(const float4*)&SB[c];
            float4 w  = *(const float4*)&SW[c];
#pragma unroll
            for (int e = 0; e < 4; ++e) {
                float ge = (&g.x)[e], be = (&bb.x)[e], we = (&w.x)[e];
                float v0 = bf2f(a0[e]) + bf2f(d0[e]) + bf2f(p0[e]);
                float v1 = bf2f(a1[e]) + bf2f(d1[e]) + bf2f(p1[e]);
                float t0 = fmaf(fmaf(v0, rsig[0], nmrs[0]), ge, be);
                float t1 = fmaf(fmaf(v1, rsig[1], nmrs[1]), ge, be);
                t0 = t0 > 0.f ? t0 : __expf(t0) - 1.f;
                t1 = t1 > 0.f ? t1 : __expf(t1) - 1.f;
                acc0e = fmaf(t0, we, acc0e);
                acc1e = fmaf(t1, we, acc1e);
            }
        }
#pragma unroll
        for (int off = 1; off < 16; off <<= 1) {
            acc0e += __shfl_xor(acc0e, off);
            acc1e += __shfl_xor(acc1e, off);
        }

        if (fl == 0) {
#pragma unroll
            for (int u = 0; u < 2; ++u) {
                if (act[u]) {
                    const int jb = ii[u] - KWIN < 0 ? 0 : ii[u] - KWIN;
                    const int n = rowstart(ii[u]) + (jj[u] - jb);
                    out[(size_t)b * NC + n] = (u ? acc1e : acc0e) + b2v;
                    if (b == 0) {
                        posout[2 * (size_t)n]     = (float)(ii[u] + 1);
                        posout[2 * (size_t)n + 1] = (float)(jj[u] + 1);
                    }
                }
            }
        }
    }
}

// ---------------------------------------------------------------------------
extern "C" void kernel_launch(void* const* d_in, const int* in_sizes, int n_in,
                              void* d_out, int out_size, void* d_ws, size_t ws_size,
                              hipStream_t stream) {
    const float* h_e     = (const float*)d_in[0];
    const float* h_c     = (const float*)d_in[1];
    const float* h_share = (const float*)d_in[2];
    // d_in[3] = mask (unused)
    const float* pos_W   = (const float*)d_in[4];
    const float* W1      = (const float*)d_in[5];
    const float* b1      = (const float*)d_in[6];
    const float* ln_g    = (const float*)d_in[7];
    const float* ln_b    = (const float*)d_in[8];
    const float* W2      = (const float*)d_in[9];
    const float* b2      = (const float*)d_in[10];

    float* ws     = (float*)d_ws;
    short* prelbf = (short*)ws;
    short* Wb     = (short*)(ws + WB_OFF);

    float* out    = (float*)d_out;
    float* posout = out + BNC;

    prep_kernel<<<15 + (2 * WNPAD * WKSTR) / 256, 256, 0, stream>>>(
        pos_W, W1, b1, prelbf, Wb);

    fused_kernel<<<NB * (L_SEQ / ITILE), 512, 0, stream>>>(
        h_e, h_c, h_share, Wb, prelbf, ln_g, ln_b, W2, b2, out, posout);
}

// Round 16
// 133.301 us; speedup vs baseline: 1.1022x; 1.1022x over previous
//
#include <hip/hip_runtime.h>
#include <hip/hip_bf16.h>
#include <math.h>

// Problem constants
#define L_SEQ   1024
#define NB      8
#define H_DIM   300
#define KWIN    5
#define NREL    11          // 2K+1
#define PDIM    50
#define NC      11234       // band pair count for L=1024, K=5
#define BNC     (NB*NC)     // 89872
#define LN_EPS  1e-5f

#define KPAD    320         // K padded with zeros in [300,320)
#define WKSTR   320         // Wb k-stride (shorts)
#define WNPAD   320         // Wb padded n rows

#define ITILE   16          // i rows per block
#define HROWS   26          // hc halo rows: i0-5 .. i0+20
#define ZROW    42          // zero rows 42..47 (MFMA clamp)
#define XROWS   64          // 0..15 Ae/he, 16..41 Ac/hc, 42..47 zero,
                            // 48..58 Pb (bf16 prel), 59 ones, 60..63 zero
#define XSTR    328         // X row stride in shorts
#define NPAIR   (ITILE*NREL)  // 176
#define NCHUNK  (HROWS*76)    // 1976 staging chunks

// Stats table layout (floats): SS[0..63], S[64..127],
// Dec[128 + row*28 + (col-16)] row<16 col 16..41,
// Dep[576 + row*12 + (col-48)] row<16 col 48..58,
// Dcp[768 + (row-16)*12 + (col-48)] row 16..41 col 48..58.  total 1080 -> 1088
#define STSZ 1088

// Workspace layout (float offsets)
#define WB_OFF   2048       // prelbf (11*328 shorts) lives at 0

typedef __attribute__((ext_vector_type(8))) short s16x8;
typedef __attribute__((ext_vector_type(4))) short s16x4;
typedef __attribute__((ext_vector_type(4))) float f32x4;

__device__ __forceinline__ short f2bf(float f) {
    unsigned u = __float_as_uint(f);
    u += 0x7fffu + ((u >> 16) & 1u);
    return (short)(u >> 16);
}
__device__ __forceinline__ float bf2f(short s) {
    return __uint_as_float(((unsigned)(unsigned short)s) << 16);
}

// band row start: first linear index n of row i
__device__ __forceinline__ int rowstart(int i) {
    if (i < 5)     return 6 * i + (i * (i - 1)) / 2;
    if (i <= 1018) return 40 + (i - 5) * 11;
    int d = i - 1019;
    return 11194 + d * 10 - (d * (d - 1)) / 2;
}

// predicated scatter of one Gram cell into the compact stats table
__device__ __forceinline__ void stat_write(float* ST, int row, int col, float v) {
    if (col == 59 && row < 59) ST[64 + row] = v;                       // S
    if (col == row && row < 59) ST[row] = v;                           // SS
    if (row < 16) {
        if (col >= 16 && col < 42)      ST[128 + row * 28 + (col - 16)] = v;  // Dec
        else if (col >= 48 && col < 59) ST[576 + row * 12 + (col - 48)] = v;  // Dep
    } else if (row < 42 && col >= 48 && col < 59) {
        ST[768 + (row - 16) * 12 + (col - 48)] = v;                    // Dcp
    }
}

// ---------------------------------------------------------------------------
// Kernel 1: prep (unchanged from r12).
__global__ __launch_bounds__(256) void prep_kernel(
    const float* __restrict__ pos_W, const float* __restrict__ W1,
    const float* __restrict__ b1, short* __restrict__ prelbf,
    short* __restrict__ Wb)
{
    if (blockIdx.x < 15) {
        __shared__ float semb[NREL * PDIM];
        for (int t = threadIdx.x; t < NREL * PDIM; t += 256) {
            int r = t / PDIM, d = t % PDIM;
            float acc = 0.f;
#pragma unroll
            for (int r2 = 0; r2 < NREL; ++r2) {
                float cnt = (float)(L_SEQ - abs(r2 - KWIN));
                int dr = r - r2;
                acc += cnt * expf(-(float)(dr * dr)) * pos_W[r2 * PDIM + d];
            }
            semb[t] = acc;
        }
        __syncthreads();
        int t = blockIdx.x * 256 + threadIdx.x;
        if (t < NREL * XSTR) {
            int r = t / XSTR, h = t % XSTR;
            float acc = 0.f;
            if (h < H_DIM) {
                acc = b1[h];
                const float* wrow = W1 + (size_t)h * 650 + 600;
                const float* em = semb + r * PDIM;
#pragma unroll 10
                for (int d = 0; d < PDIM; ++d) acc += wrow[d] * em[d];
            }
            prelbf[t] = (h < H_DIM) ? f2bf(acc) : (short)0;
        }
    } else {
        int id = (blockIdx.x - 15) * 256 + threadIdx.x;
        if (id < 2 * WNPAD * WKSTR) {
            int z = id / (WNPAD * WKSTR);
            int rem = id % (WNPAD * WKSTR);
            int n = rem / WKSTR, k = rem % WKSTR;
            float v = (n < H_DIM && k < H_DIM) ? W1[(size_t)n * 650 + z * H_DIM + k] : 0.f;
            Wb[id] = f2bf(v);
        }
    }
}

// ---------------------------------------------------------------------------
// Kernel 2: fused GEMM + Gram(compact stats) + single-pair epilogue.
// Block = (b, i-tile of 16), 512 threads, grid 512.
// LDS ~48 KB -> 3 blocks/CU (24 waves/CU); single-pair epilogue keeps
// VGPR ~52-64 (r13/r15 lesson: dual-pair epilogue => 120 VGPR => cliff).
__global__ __launch_bounds__(512) void fused_kernel(
    const float* __restrict__ h_e, const float* __restrict__ h_c,
    const float* __restrict__ h_share, const short* __restrict__ Wb,
    const short* __restrict__ prelbf,
    const float* __restrict__ ln_g, const float* __restrict__ ln_b,
    const float* __restrict__ W2, const float* __restrict__ b2,
    float* __restrict__ out, float* __restrict__ posout)
{
    __shared__ __align__(16) short X[XROWS * XSTR];   // 41984 B
    __shared__ __align__(16) float ST[STSZ];          // 4352 B
    __shared__ __align__(16) float SG[320];
    __shared__ __align__(16) float SB[320];
    __shared__ __align__(16) float SW[320];

    const int tid = threadIdx.x;
    const int b   = blockIdx.x >> 6;
    const int i0  = (blockIdx.x & 63) * ITILE;

    // ---- zero-fill: rows 42..47 & 60..63 (10*41 chunks) + rows 0..41 cols [304,328)
    for (int t = tid; t < 536; t += 512) {
        int row, c;
        if (t < 410) { int rr2 = t / 41; row = rr2 < 6 ? 42 + rr2 : 60 + (rr2 - 6); c = (t % 41) * 8; }
        else         { int u = t - 410; row = u / 3; c = 304 + (u % 3) * 8; }
        *(s16x8*)&X[row * XSTR + c] = (s16x8){0,0,0,0,0,0,0,0};
    }
    // ---- ones row (59)
    for (int t = tid; t < XSTR; t += 512)
        X[59 * XSTR + t] = (t < H_DIM) ? (short)0x3F80 : (short)0;
    // ---- Pb rows 48..58
    for (int t = tid; t < NREL * 41; t += 512) {
        int r = t / 41, c = (t % 41) * 8;
        *(s16x8*)&X[(48 + r) * XSTR + c] = *(const s16x8*)(prelbf + r * XSTR + c);
    }
    // ---- LN params
    if (tid < 320) {
        bool v = tid < H_DIM;
        SG[tid] = v ? ln_g[tid] : 0.f;
        SB[tid] = v ? ln_b[tid] : 0.f;
        SW[tid] = v ? W2[tid]   : 0.f;
    }
    // ---- stage 26 halo rows; h_share read once per row.
    for (int t = tid; t < NCHUNK; t += 512) {
        int s = t / 76, kc = (t % 76) * 4;
        int g = i0 - KWIN + s;
        bool valid = (kc < H_DIM) && (g >= 0) && (g < L_SEQ);
        float4 hs4 = make_float4(0.f,0.f,0.f,0.f), hc4 = hs4;
        size_t off = 0;
        if (valid) {
            off = ((size_t)b * L_SEQ + g) * H_DIM + kc;
            hs4 = *(const float4*)(h_share + off);
            hc4 = *(const float4*)(h_c + off);
        }
        s16x4 vc = { f2bf(hc4.x + hs4.x), f2bf(hc4.y + hs4.y),
                     f2bf(hc4.z + hs4.z), f2bf(hc4.w + hs4.w) };
        *(s16x4*)&X[(16 + s) * XSTR + kc] = vc;
        if (s >= 5 && s < 5 + ITILE) {
            float4 he4 = make_float4(0.f,0.f,0.f,0.f);
            if (valid) he4 = *(const float4*)(h_e + off);
            s16x4 ve = { f2bf(he4.x + hs4.x), f2bf(he4.y + hs4.y),
                         f2bf(he4.z + hs4.z), f2bf(he4.w + hs4.w) };
            *(s16x4*)&X[(s - 5) * XSTR + kc] = ve;
        }
    }
    __syncthreads();

    // ---- Main GEMM (r12 structure). 8 waves: wz = wave>>2, nsl = (wave&3)*80.
    const int wave = tid >> 6, lane = tid & 63;
    const int fr = lane & 15, fq = lane >> 4;
    const int wz  = wave >> 2;
    const int nsl = (wave & 3) * 80;
    const short* wbase = Wb + ((size_t)(wz * WNPAD + nsl + fr)) * WKSTR + fq * 8;

    const int mrow0 = wz ? (16 + fr) : fr;
    const int mrow1 = (fr < 10) ? (32 + fr) : ZROW;   // wz==1 only

    f32x4 acc0[5] = {};
    f32x4 acc1[5] = {};

    for (int k0 = 0; k0 < KPAD; k0 += 32) {
        s16x8 bf[5];
#pragma unroll
        for (int nt = 0; nt < 5; ++nt)
            bf[nt] = *(const s16x8*)(wbase + (size_t)nt * 16 * WKSTR + k0);
        s16x8 af0 = *(const s16x8*)&X[mrow0 * XSTR + k0 + fq * 8];
#pragma unroll
        for (int nt = 0; nt < 5; ++nt)
            acc0[nt] = __builtin_amdgcn_mfma_f32_16x16x32_bf16(af0, bf[nt], acc0[nt], 0, 0, 0);
        if (wz) {
            s16x8 af1 = *(const s16x8*)&X[mrow1 * XSTR + k0 + fq * 8];
#pragma unroll
            for (int nt = 0; nt < 5; ++nt)
                acc1[nt] = __builtin_amdgcn_mfma_f32_16x16x32_bf16(af1, bf[nt], acc1[nt], 0, 0, 0);
        }
    }
    __syncthreads();   // all waves done reading X inputs

    // ---- write Ae/Ac into X (bf16). C/D: col = nsl+nt*16+fr, row = fq*4+r2
#pragma unroll
    for (int nt = 0; nt < 5; ++nt) {
        const int col = nsl + nt * 16 + fr;     // cols>=300 compute to 0
        if (!wz) {
#pragma unroll
            for (int r2 = 0; r2 < 4; ++r2)
                X[(fq * 4 + r2) * XSTR + col] = f2bf(acc0[nt][r2]);
        } else {
#pragma unroll
            for (int r2 = 0; r2 < 4; ++r2)
                X[(16 + fq * 4 + r2) * XSTR + col] = f2bf(acc0[nt][r2]);
#pragma unroll
            for (int r2 = 0; r2 < 4; ++r2) {
                int rw = 32 + fq * 4 + r2;
                if (rw < 42) X[rw * XSTR + col] = f2bf(acc1[nt][r2]);
            }
        }
    }
    __syncthreads();

    // ---- Gram mini-GEMM: G = X . X^T over 64 rows, scatter needed stats only.
    {
        const int mf  = wave & 3;
        const int nf0 = (wave >> 2) * 2;
        f32x4 ga = {}, gb = {};
        for (int k0 = 0; k0 < KPAD; k0 += 32) {
            s16x8 av = *(const s16x8*)&X[(mf * 16 + fr) * XSTR + k0 + fq * 8];
            s16x8 b0 = *(const s16x8*)&X[(nf0 * 16 + fr) * XSTR + k0 + fq * 8];
            s16x8 b1 = *(const s16x8*)&X[((nf0 + 1) * 16 + fr) * XSTR + k0 + fq * 8];
            ga = __builtin_amdgcn_mfma_f32_16x16x32_bf16(av, b0, ga, 0, 0, 0);
            gb = __builtin_amdgcn_mfma_f32_16x16x32_bf16(av, b1, gb, 0, 0, 0);
        }
        const int col0 = nf0 * 16 + fr, col1 = col0 + 16;
#pragma unroll
        for (int r2 = 0; r2 < 4; ++r2) {
            const int row = mf * 16 + fq * 4 + r2;
            stat_write(ST, row, col0, ga[r2]);
            stat_write(ST, row, col1, gb[r2]);
        }
    }
    __syncthreads();

    // ---- Epilogue: 1 pair per 16-lane quad, 32 quads, 6 rounds (176 pairs).
    const int quad = lane >> 4, fl = lane & 15;
    const int qq = wave * 4 + quad;            // 0..31
    const float b2v = b2[0];
    const float inv = 1.f / (float)H_DIM;

    for (int round = 0; round < 6; ++round) {
        const int q = round * 32 + qq;          // 0..191
        const int qc = q < NPAIR - 1 ? q : NPAIR - 1;
        const int di = qc / NREL, rr = qc % NREL;
        const int ii = i0 + di, j = ii - KWIN + rr;
        const bool active = (q < NPAIR) && (j >= 0) && (j < L_SEQ);

        const int iA = di;                 // Ae row in X
        const int jA = 16 + di + rr;       // Ac row
        const int pA = 48 + rr;            // Pb row

        const float Se  = ST[64 + iA];
        const float Sc  = ST[64 + jA];
        const float Sp  = ST[64 + pA];
        const float SSe = ST[iA];
        const float SSc = ST[jA];
        const float SSp = ST[pA];
        const float Dec = ST[128 + iA * 28 + (jA - 16)];
        const float Dep = ST[576 + iA * 12 + rr];
        const float Dcp = ST[768 + (jA - 16) * 12 + rr];

        const float mu   = (Se + Sc + Sp) * inv;
        const float ssv  = SSe + SSc + SSp + 2.f * (Dec + Dep + Dcp);
        const float rsig = rsqrtf(ssv * inv - mu * mu + LN_EPS);
        const float nmrs = -mu * rsig;

        const int ea = iA * XSTR, ca = jA * XSTR, pa = pA * XSTR;

        float acc2 = 0.f;
#pragma unroll
        for (int w5 = 0; w5 < 5; ++w5) {
            const int c = w5 * 64 + fl * 4;     // 0..316, zero-padded
            s16x4 a0 = *(const s16x4*)&X[ea + c];
            s16x4 d0 = *(const s16x4*)&X[ca + c];
            s16x4 p0 = *(const s16x4*)&X[pa + c];
            float4 g  = *(const float4*)&SG[c];
            float4 bb = *(const float4*)&SB[c];
            float4 w  = *(const float4*)&SW[c];
#pragma unroll
            for (int e = 0; e < 4; ++e) {
                float v = bf2f(a0[e]) + bf2f(d0[e]) + bf2f(p0[e]);
                float t0 = fmaf(fmaf(v, rsig, nmrs), (&g.x)[e], (&bb.x)[e]);
                t0 = t0 > 0.f ? t0 : __expf(t0) - 1.f;
                acc2 = fmaf(t0, (&w.x)[e], acc2);
            }
        }
#pragma unroll
        for (int off = 1; off < 16; off <<= 1) acc2 += __shfl_xor(acc2, off);

        if (fl == 0 && active) {
            const int jb = ii - KWIN < 0 ? 0 : ii - KWIN;
            const int n = rowstart(ii) + (j - jb);
            out[(size_t)b * NC + n] = acc2 + b2v;
            if (b == 0) {
                posout[2 * (size_t)n]     = (float)(ii + 1);
                posout[2 * (size_t)n + 1] = (float)(j + 1);
            }
        }
    }
}

// ---------------------------------------------------------------------------
extern "C" void kernel_launch(void* const* d_in, const int* in_sizes, int n_in,
                              void* d_out, int out_size, void* d_ws, size_t ws_size,
                              hipStream_t stream) {
    const float* h_e     = (const float*)d_in[0];
    const float* h_c     = (const float*)d_in[1];
    const float* h_share = (const float*)d_in[2];
    // d_in[3] = mask (unused)
    const float* pos_W   = (const float*)d_in[4];
    const float* W1      = (const float*)d_in[5];
    const float* b1      = (const float*)d_in[6];
    const float* ln_g    = (const float*)d_in[7];
    const float* ln_b    = (const float*)d_in[8];
    const float* W2      = (const float*)d_in[9];
    const float* b2      = (const float*)d_in[10];

    float* ws     = (float*)d_ws;
    short* prelbf = (short*)ws;
    short* Wb     = (short*)(ws + WB_OFF);

    float* out    = (float*)d_out;
    float* posout = out + BNC;

    prep_kernel<<<15 + (2 * WNPAD * WKSTR) / 256, 256, 0, stream>>>(
        pos_W, W1, b1, prelbf, Wb);

    fused_kernel<<<NB * (L_SEQ / ITILE), 512, 0, stream>>>(
        h_e, h_c, h_share, Wb, prelbf, ln_g, ln_b, W2, b2, out, posout);
}